// Round 1
// baseline (636.785 us; speedup 1.0000x reference)
//
#include <hip/hip_runtime.h>
#include <stdint.h>

// Problem constants (fixed by the reference).
#define L_EXPERTS 4
#define D_IN  2048
#define D_OUT 2048
#define B_TOK 16384

using f32x4  = __attribute__((ext_vector_type(4))) float;
using bf16x8 = __attribute__((ext_vector_type(8))) short;

__device__ __forceinline__ uint32_t f2bf(float f) {
    union { float f; uint32_t u; } v; v.f = f;
    uint32_t u = v.u;
    return (u + 0x7fffu + ((u >> 16) & 1u)) >> 16;   // RNE, no NaN inputs expected
}

__device__ __forceinline__ void gl_lds16(const void* g, void* l) {
    __builtin_amdgcn_global_load_lds(
        (const __attribute__((address_space(1))) void*)g,
        (__attribute__((address_space(3))) void*)l, 16, 0, 0);
}

// ---------------------------------------------------------------------------
// Kernel 1: counting sort of tokens by expert. One block, 256 threads.
// meta[0..4] = exclusive prefix of per-expert counts; perm[pos] = token id.
// ---------------------------------------------------------------------------
__global__ void sort_tokens(const int* __restrict__ idx,
                            int* __restrict__ meta, int* __restrict__ perm) {
    __shared__ int s_cnt[L_EXPERTS];
    __shared__ int s_off[L_EXPERTS + 1];
    __shared__ int s_cur[L_EXPERTS];
    const int tid = threadIdx.x;
    if (tid < L_EXPERTS) s_cnt[tid] = 0;
    __syncthreads();

    int c[L_EXPERTS] = {0, 0, 0, 0};
    for (int i = tid; i < B_TOK; i += 256) {
        int e = idx[i];
        #pragma unroll
        for (int ee = 0; ee < L_EXPERTS; ++ee) c[ee] += (e == ee);
    }
    #pragma unroll
    for (int ee = 0; ee < L_EXPERTS; ++ee) atomicAdd(&s_cnt[ee], c[ee]);
    __syncthreads();

    if (tid == 0) {
        int o = 0;
        for (int ee = 0; ee < L_EXPERTS; ++ee) {
            s_off[ee] = o; meta[ee] = o; o += s_cnt[ee];
        }
        s_off[L_EXPERTS] = o; meta[L_EXPERTS] = o;   // == B_TOK
    }
    __syncthreads();
    if (tid < L_EXPERTS) s_cur[tid] = s_off[tid];
    __syncthreads();

    const int lane = tid & 63;
    const unsigned long long lt_mask = (1ull << lane) - 1ull;
    for (int i = tid; i < B_TOK; i += 256) {           // uniform trip count
        int e = idx[i];
        int pos = 0;
        #pragma unroll
        for (int ee = 0; ee < L_EXPERTS; ++ee) {
            unsigned long long m = __ballot(e == ee);
            if (m) {
                int leader = __ffsll((unsigned long long)m) - 1;
                int base = 0;
                if (lane == leader) base = atomicAdd(&s_cur[ee], __popcll(m));
                base = __shfl(base, leader);
                if (e == ee) pos = base + __popcll(m & lt_mask);
            }
        }
        perm[pos] = i;
    }
}

// ---------------------------------------------------------------------------
// Kernel 2: gather x rows in perm order, convert fp32 -> bf16.
// One block per output row; 16 B loads + 16 B stores per thread.
// ---------------------------------------------------------------------------
__global__ void gather_convert(const float* __restrict__ x,
                               const int* __restrict__ perm,
                               uint32_t* __restrict__ Ag /* bf16 pairs */) {
    const int p = blockIdx.x;
    const int t = perm[p];
    const float4* src = (const float4*)(x + (size_t)t * D_IN);
    uint4* dst = (uint4*)(Ag + (size_t)p * (D_IN / 2));
    const int j = threadIdx.x;                 // 256 threads, 8 floats each
    float4 v0 = src[2 * j], v1 = src[2 * j + 1];
    uint4 o;
    o.x = f2bf(v0.x) | (f2bf(v0.y) << 16);
    o.y = f2bf(v0.z) | (f2bf(v0.w) << 16);
    o.z = f2bf(v1.x) | (f2bf(v1.y) << 16);
    o.w = f2bf(v1.z) | (f2bf(v1.w) << 16);
    dst[j] = o;
}

// ---------------------------------------------------------------------------
// Kernel 3: W [l][k][n] fp32 -> Wt [l][n][k] bf16 (tiled transpose).
// grid (64, 64, 4), block (32, 8).
// ---------------------------------------------------------------------------
__global__ void wtrans(const float* __restrict__ W, ushort* __restrict__ Wt) {
    __shared__ float tile[32][33];
    const int l  = blockIdx.z;
    const int k0 = blockIdx.x * 32;
    const int n0 = blockIdx.y * 32;
    const float* Wl = W + (size_t)l * D_IN * D_OUT;
    ushort* Wtl = Wt + (size_t)l * D_IN * D_OUT;
    const int tx = threadIdx.x, ty = threadIdx.y;
    #pragma unroll
    for (int i = 0; i < 32; i += 8)
        tile[ty + i][tx] = Wl[(size_t)(k0 + ty + i) * D_OUT + n0 + tx];
    __syncthreads();
    #pragma unroll
    for (int i = 0; i < 32; i += 8)
        Wtl[(size_t)(n0 + ty + i) * D_IN + k0 + tx] = (ushort)f2bf(tile[tx][ty + i]);
}

// ---------------------------------------------------------------------------
// Kernel 4: grouped GEMM. 128x128 tile, BK=64, 4 waves, 16x16x32 bf16 MFMA.
// LDS chunk layout: chunk = 16 rows x 32 k = 64 lanes x 16 B, lane-ordered,
// so every ds_read_b128 is conflict-free and global_load_lds staging is a
// per-lane 16 B gather into lane-contiguous LDS slots.
// ---------------------------------------------------------------------------
__global__ __launch_bounds__(256, 2)
void gemm_grouped(const ushort* __restrict__ Ag, const ushort* __restrict__ Wt,
                  const float* __restrict__ bias, const int* __restrict__ meta,
                  const int* __restrict__ perm, float* __restrict__ out) {
    __shared__ __align__(16) ushort smem[32 * 512];   // 32 KB: 16 A + 16 B chunks

    int off[L_EXPERTS + 1];
    #pragma unroll
    for (int i = 0; i <= L_EXPERTS; ++i) off[i] = meta[i];

    // Map blockIdx.x -> (expert, local m-tile)
    const int mt = blockIdx.x;
    int e = -1, lt = 0, t0 = 0;
    #pragma unroll
    for (int i = 0; i < L_EXPERTS; ++i) {
        int cnt = off[i + 1] - off[i];
        int tiles = (cnt + 127) >> 7;
        if (e < 0 && mt < t0 + tiles) { e = i; lt = mt - t0; }
        t0 += tiles;
    }
    if (e < 0) return;
    const int rowbase = off[e] + lt * 128;
    const int cnt_e   = off[e + 1] - off[e];
    const int n0      = blockIdx.y * 128;

    const int tid  = threadIdx.x;
    const int lane = tid & 63;
    const int w    = tid >> 6;
    const int wm   = w & 1, wn = w >> 1;
    const int l15  = lane & 15, lq = lane >> 4;

    f32x4 acc[4][4] = {};

    for (int k0 = 0; k0 < D_IN; k0 += 64) {
        if (k0) __syncthreads();
        #pragma unroll
        for (int q = 0; q < 8; ++q) {
            const int cidx = w * 8 + q;            // wave-uniform chunk id
            const ushort* gp;
            if (cidx < 16) {                        // A chunk: s=cidx>>3, cm=cidx&7
                int s = cidx >> 3, cm = cidx & 7;
                int row = rowbase + cm * 16 + l15;
                gp = Ag + (size_t)row * D_IN + k0 + s * 32 + lq * 8;
            } else {                                // B chunk
                int cb = cidx - 16;
                int s = cb >> 3, cn = cb & 7;
                int col = n0 + cn * 16 + l15;
                gp = Wt + ((size_t)e * D_OUT + col) * D_IN + k0 + s * 32 + lq * 8;
            }
            gl_lds16(gp, &smem[cidx * 512]);
        }
        __syncthreads();
        #pragma unroll
        for (int s = 0; s < 2; ++s) {
            bf16x8 af[4], bf[4];
            #pragma unroll
            for (int i = 0; i < 4; ++i)
                af[i] = *(const bf16x8*)&smem[(s * 8 + wm * 4 + i) * 512 + lane * 8];
            #pragma unroll
            for (int j = 0; j < 4; ++j)
                bf[j] = *(const bf16x8*)&smem[(16 + s * 8 + wn * 4 + j) * 512 + lane * 8];
            #pragma unroll
            for (int i = 0; i < 4; ++i)
                #pragma unroll
                for (int j = 0; j < 4; ++j)
                    acc[i][j] = __builtin_amdgcn_mfma_f32_16x16x32_bf16(
                        af[i], bf[j], acc[i][j], 0, 0, 0);
        }
    }

    // Epilogue: bias add + scatter through perm. C layout: col=lane&15,
    // row = lq*4 + r (verified m89/m91).
    float bv[4];
    #pragma unroll
    for (int j = 0; j < 4; ++j)
        bv[j] = bias[(size_t)e * D_OUT + n0 + wn * 64 + j * 16 + l15];
    #pragma unroll
    for (int i = 0; i < 4; ++i) {
        #pragma unroll
        for (int r = 0; r < 4; ++r) {
            int lr = lt * 128 + wm * 64 + i * 16 + lq * 4 + r;
            if (lr < cnt_e) {
                int tok = perm[off[e] + lr];
                float* orow = out + (size_t)tok * D_OUT + n0 + wn * 64 + l15;
                #pragma unroll
                for (int j = 0; j < 4; ++j)
                    orow[j * 16] = acc[i][j][r] + bv[j];
            }
        }
    }
}

// ---------------------------------------------------------------------------
// Fallback (only if ws_size is too small): naive fp32, correct but slow.
// ---------------------------------------------------------------------------
__global__ void fallback_kernel(const float* __restrict__ x, const int* __restrict__ idx,
                                const float* __restrict__ W, const float* __restrict__ bias,
                                float* __restrict__ out) {
    __shared__ float xs[D_IN];
    const int t = blockIdx.x;
    const int e = idx[t];
    const float* xr = x + (size_t)t * D_IN;
    for (int k = threadIdx.x; k < D_IN; k += 256) xs[k] = xr[k];
    __syncthreads();
    const float* We = W + (size_t)e * D_IN * D_OUT;
    #pragma unroll 2
    for (int j = 0; j < D_OUT / 256; ++j) {
        int col = threadIdx.x + j * 256;
        float a = bias[(size_t)e * D_OUT + col];
        for (int k = 0; k < D_IN; ++k) a += xs[k] * We[(size_t)k * D_OUT + col];
        out[(size_t)t * D_OUT + col] = a;
    }
}

// ---------------------------------------------------------------------------
extern "C" void kernel_launch(void* const* d_in, const int* in_sizes, int n_in,
                              void* d_out, int out_size, void* d_ws, size_t ws_size,
                              hipStream_t stream) {
    const float* x   = (const float*)d_in[0];
    const int*   idx = (const int*)d_in[1];
    const float* W   = (const float*)d_in[2];
    const float* b   = (const float*)d_in[3];
    float* out = (float*)d_out;

    // ws layout: [meta 256B][perm 64KB][Ag (B+128)*2048 bf16][Wt 4*2048*2048 bf16]
    const size_t META_OFF = 0;
    const size_t PERM_OFF = 256;
    const size_t AG_OFF   = PERM_OFF + (size_t)B_TOK * 4;
    const size_t AG_BYTES = (size_t)(B_TOK + 128) * D_IN * 2;
    const size_t WT_OFF   = AG_OFF + AG_BYTES;
    const size_t WT_BYTES = (size_t)L_EXPERTS * D_IN * D_OUT * 2;
    const size_t NEED     = WT_OFF + WT_BYTES;        // ~96.6 MB

    if (ws_size < NEED) {   // launch-invariant branch: graph-safe
        fallback_kernel<<<B_TOK, 256, 0, stream>>>(x, idx, W, b, out);
        return;
    }

    int*      meta = (int*)((char*)d_ws + META_OFF);
    int*      perm = (int*)((char*)d_ws + PERM_OFF);
    uint32_t* Ag   = (uint32_t*)((char*)d_ws + AG_OFF);
    ushort*   Wt   = (ushort*)((char*)d_ws + WT_OFF);

    sort_tokens<<<1, 256, 0, stream>>>(idx, meta, perm);
    gather_convert<<<B_TOK, 256, 0, stream>>>(x, perm, Ag);
    wtrans<<<dim3(64, 64, L_EXPERTS), dim3(32, 8), 0, stream>>>(W, Wt);
    // max m-tiles = sum_e ceil(cnt_e/128) <= 131; grid.x = 132 with early-out
    gemm_grouped<<<dim3(132, D_OUT / 128), 256, 0, stream>>>(
        (const ushort*)Ag, Wt, b, meta, perm, out);
}

// Round 2
// 566.917 us; speedup vs baseline: 1.1232x; 1.1232x over previous
//
#include <hip/hip_runtime.h>
#include <stdint.h>

// Problem constants (fixed by the reference).
#define L_EXPERTS 4
#define D_IN  2048
#define D_OUT 2048
#define B_TOK 16384

using f32x4  = __attribute__((ext_vector_type(4))) float;
using bf16x8 = __attribute__((ext_vector_type(8))) short;

__device__ __forceinline__ uint32_t f2bf(float f) {
    union { float f; uint32_t u; } v; v.f = f;
    uint32_t u = v.u;
    return (u + 0x7fffu + ((u >> 16) & 1u)) >> 16;   // RNE
}

__device__ __forceinline__ void gl_lds16(const void* g, void* l) {
    __builtin_amdgcn_global_load_lds(
        (const __attribute__((address_space(1))) void*)g,
        (__attribute__((address_space(3))) void*)l, 16, 0, 0);
}

// ---------------------------------------------------------------------------
// Sort stage A: per-block histograms (no atomics, no pre-zeroing needed).
// grid 64 x 256: one token per thread.
// ---------------------------------------------------------------------------
__global__ void hist_kernel(const int* __restrict__ idx, int* __restrict__ hist) {
    __shared__ int h[L_EXPERTS];
    if (threadIdx.x < L_EXPERTS) h[threadIdx.x] = 0;
    __syncthreads();
    const int e = idx[blockIdx.x * 256 + threadIdx.x];
    atomicAdd(&h[e], 1);
    __syncthreads();
    if (threadIdx.x < L_EXPERTS)
        hist[blockIdx.x * L_EXPERTS + threadIdx.x] = h[threadIdx.x];
}

// Sort stage B: reduce + exclusive prefix -> meta[0..4], cursor[0..3]. 1 block.
__global__ void prefix_kernel(const int* __restrict__ hist,
                              int* __restrict__ meta, int* __restrict__ cursor) {
    __shared__ int tot[L_EXPERTS];
    if (threadIdx.x < L_EXPERTS) {
        int s = 0;
        for (int b = 0; b < 64; ++b) s += hist[b * L_EXPERTS + threadIdx.x];
        tot[threadIdx.x] = s;
    }
    __syncthreads();
    if (threadIdx.x == 0) {
        int o = 0;
        for (int e = 0; e < L_EXPERTS; ++e) {
            meta[e] = o; cursor[e] = o; o += tot[e];
        }
        meta[L_EXPERTS] = o;   // == B_TOK
    }
}

// Sort stage C: ballot-aggregated scatter. Order within expert is irrelevant
// (out[j] depends only on which expert j got). grid 64 x 256.
__global__ void scatter_kernel(const int* __restrict__ idx,
                               int* __restrict__ cursor, int* __restrict__ perm) {
    const int i = blockIdx.x * 256 + threadIdx.x;
    const int e = idx[i];
    const int lane = threadIdx.x & 63;
    const unsigned long long lt_mask = (1ull << lane) - 1ull;
    int pos = 0;
    #pragma unroll
    for (int ee = 0; ee < L_EXPERTS; ++ee) {
        unsigned long long m = __ballot(e == ee);
        if (m) {
            int leader = __ffsll(m) - 1;
            int base = 0;
            if (lane == leader) base = atomicAdd(&cursor[ee], __popcll(m));
            base = __shfl(base, leader);
            if (e == ee) pos = base + __popcll(m & lt_mask);
        }
    }
    perm[pos] = i;
}

// ---------------------------------------------------------------------------
// Gather x rows in perm order, convert fp32 -> bf16. One block per row.
// ---------------------------------------------------------------------------
__global__ void gather_convert(const float* __restrict__ x,
                               const int* __restrict__ perm,
                               uint32_t* __restrict__ Ag) {
    const int p = blockIdx.x;
    const int t = perm[p];
    const float4* src = (const float4*)(x + (size_t)t * D_IN);
    uint4* dst = (uint4*)(Ag + (size_t)p * (D_IN / 2));
    const int j = threadIdx.x;                 // 256 threads, 8 floats each
    float4 v0 = src[2 * j], v1 = src[2 * j + 1];
    uint4 o;
    o.x = f2bf(v0.x) | (f2bf(v0.y) << 16);
    o.y = f2bf(v0.z) | (f2bf(v0.w) << 16);
    o.z = f2bf(v1.x) | (f2bf(v1.y) << 16);
    o.w = f2bf(v1.z) | (f2bf(v1.w) << 16);
    dst[j] = o;
}

// ---------------------------------------------------------------------------
// W [l][k][n] fp32 -> Wt [l][n][k] bf16. 64x64 tiles, float4 loads,
// 16 B packed stores (R1's 2 B stores were the prep bottleneck).
// grid (32, 32, 4), block 256.
// ---------------------------------------------------------------------------
__global__ void wtrans(const float* __restrict__ W, ushort* __restrict__ Wt) {
    __shared__ float tile[64][65];
    const int l  = blockIdx.z;
    const int k0 = blockIdx.x * 64, n0 = blockIdx.y * 64;
    const float* Wl = W + (size_t)l * D_IN * D_OUT;
    ushort* Wtl = Wt + (size_t)l * D_IN * D_OUT;
    const int t = threadIdx.x;
    const int kr = t >> 4, nc = (t & 15) * 4;
    #pragma unroll
    for (int i = 0; i < 64; i += 16) {
        float4 v = *(const float4*)&Wl[(size_t)(k0 + kr + i) * D_OUT + n0 + nc];
        tile[kr + i][nc]     = v.x; tile[kr + i][nc + 1] = v.y;
        tile[kr + i][nc + 2] = v.z; tile[kr + i][nc + 3] = v.w;
    }
    __syncthreads();
    const int nr = t >> 3, kc = (t & 7) * 8;
    #pragma unroll
    for (int i = 0; i < 64; i += 32) {
        uint4 o;
        o.x = f2bf(tile[kc + 0][nr + i]) | (f2bf(tile[kc + 1][nr + i]) << 16);
        o.y = f2bf(tile[kc + 2][nr + i]) | (f2bf(tile[kc + 3][nr + i]) << 16);
        o.z = f2bf(tile[kc + 4][nr + i]) | (f2bf(tile[kc + 5][nr + i]) << 16);
        o.w = f2bf(tile[kc + 6][nr + i]) | (f2bf(tile[kc + 7][nr + i]) << 16);
        *(uint4*)&Wtl[(size_t)(n0 + nr + i) * D_IN + k0 + kc] = o;
    }
}

// ---------------------------------------------------------------------------
// Grouped GEMM. 128x128 tile, BK=32, double-buffered LDS (2 x 16 KB),
// single barrier per K-iter: issue stage k+1 after the barrier, compute
// stage k, trailing barrier drains -> exposed latency = Lat - compute.
// 1D grid with 8m x 16n supertile swizzle for k-synchronized L2 reuse.
// ---------------------------------------------------------------------------
__global__ __launch_bounds__(256, 3)
void gemm_grouped(const ushort* __restrict__ Ag, const ushort* __restrict__ Wt,
                  const float* __restrict__ bias, const int* __restrict__ meta,
                  const int* __restrict__ perm, float* __restrict__ out) {
    __shared__ __align__(16) ushort smem[2 * 16 * 512];   // 32 KB

    int off[L_EXPERTS + 1];
    #pragma unroll
    for (int i = 0; i <= L_EXPERTS; ++i) off[i] = meta[i];

    // Swizzle: supertile = 8 m-tiles x 16 n-tiles = 128 blocks, m fastest.
    const int gid = blockIdx.x;
    const int mt = (gid >> 7) * 8 + (gid & 7);
    const int nt = (gid & 127) >> 3;

    int e = -1, lt = 0, t0 = 0;
    #pragma unroll
    for (int i = 0; i < L_EXPERTS; ++i) {
        int cnt = off[i + 1] - off[i];
        int tiles = (cnt + 127) >> 7;
        if (e < 0 && mt < t0 + tiles) { e = i; lt = mt - t0; }
        t0 += tiles;
    }
    if (e < 0) return;                      // padding blocks
    const int rowbase = off[e] + lt * 128;
    const int cnt_e   = off[e + 1] - off[e];
    const int n0      = nt * 128;

    const int tid  = threadIdx.x;
    const int lane = tid & 63;
    const int w    = tid >> 6;
    const int wm   = w & 1, wn = w >> 1;
    const int l15  = lane & 15, lq = lane >> 4;

    // Per-wave staging pointers: 4 chunks of 16(rows|cols) x 32 k = 1 KB each.
    const ushort* gp[4];
    #pragma unroll
    for (int q = 0; q < 4; ++q) {
        const int cidx = w * 4 + q;                 // wave-uniform chunk id
        if (cidx < 8) {                              // A chunk
            int row = rowbase + cidx * 16 + l15;
            gp[q] = Ag + (size_t)row * D_IN + lq * 8;
        } else {                                     // B chunk
            int col = n0 + (cidx - 8) * 16 + l15;
            gp[q] = Wt + ((size_t)e * D_OUT + col) * D_IN + lq * 8;
        }
    }

    f32x4 acc[4][4] = {};
    const int NK = D_IN / 32;                        // 64 stages

    // Prefetch stage 0 into buffer 0.
    #pragma unroll
    for (int q = 0; q < 4; ++q)
        gl_lds16(gp[q], &smem[(w * 4 + q) * 512]);
    __syncthreads();

    for (int k = 0; k < NK; ++k) {
        if (k + 1 < NK) {                            // issue stage k+1
            const int nb = (k + 1) & 1;
            #pragma unroll
            for (int q = 0; q < 4; ++q)
                gl_lds16(gp[q] + (k + 1) * 32,
                         &smem[(nb * 16 + w * 4 + q) * 512]);
        }
        const ushort* base = &smem[(k & 1) * 16 * 512];
        bf16x8 af[4], bg[4];
        #pragma unroll
        for (int i = 0; i < 4; ++i)
            af[i] = *(const bf16x8*)&base[(wm * 4 + i) * 512 + lane * 8];
        #pragma unroll
        for (int j = 0; j < 4; ++j)
            bg[j] = *(const bf16x8*)&base[(8 + wn * 4 + j) * 512 + lane * 8];
        #pragma unroll
        for (int i = 0; i < 4; ++i)
            #pragma unroll
            for (int j = 0; j < 4; ++j)
                acc[i][j] = __builtin_amdgcn_mfma_f32_16x16x32_bf16(
                    af[i], bg[j], acc[i][j], 0, 0, 0);
        __syncthreads();                             // drains stage k+1 loads
    }

    // Epilogue: bias + scatter through perm. C layout: col=lane&15, row=lq*4+r.
    float bv[4];
    #pragma unroll
    for (int j = 0; j < 4; ++j)
        bv[j] = bias[(size_t)e * D_OUT + n0 + wn * 64 + j * 16 + l15];
    #pragma unroll
    for (int i = 0; i < 4; ++i) {
        #pragma unroll
        for (int r = 0; r < 4; ++r) {
            int lr = lt * 128 + wm * 64 + i * 16 + lq * 4 + r;
            if (lr < cnt_e) {
                int tok = perm[off[e] + lr];
                float* orow = out + (size_t)tok * D_OUT + n0 + wn * 64 + l15;
                #pragma unroll
                for (int j = 0; j < 4; ++j)
                    orow[j * 16] = acc[i][j][r] + bv[j];
            }
        }
    }
}

// ---------------------------------------------------------------------------
// Fallback (only if ws_size is too small): naive fp32, correct but slow.
// ---------------------------------------------------------------------------
__global__ void fallback_kernel(const float* __restrict__ x, const int* __restrict__ idx,
                                const float* __restrict__ W, const float* __restrict__ bias,
                                float* __restrict__ out) {
    __shared__ float xs[D_IN];
    const int t = blockIdx.x;
    const int e = idx[t];
    const float* xr = x + (size_t)t * D_IN;
    for (int k = threadIdx.x; k < D_IN; k += 256) xs[k] = xr[k];
    __syncthreads();
    const float* We = W + (size_t)e * D_IN * D_OUT;
    #pragma unroll 2
    for (int j = 0; j < D_OUT / 256; ++j) {
        int col = threadIdx.x + j * 256;
        float a = bias[(size_t)e * D_OUT + col];
        for (int k = 0; k < D_IN; ++k) a += xs[k] * We[(size_t)k * D_OUT + col];
        out[(size_t)t * D_OUT + col] = a;
    }
}

// ---------------------------------------------------------------------------
extern "C" void kernel_launch(void* const* d_in, const int* in_sizes, int n_in,
                              void* d_out, int out_size, void* d_ws, size_t ws_size,
                              hipStream_t stream) {
    const float* x   = (const float*)d_in[0];
    const int*   idx = (const int*)d_in[1];
    const float* W   = (const float*)d_in[2];
    const float* b   = (const float*)d_in[3];
    float* out = (float*)d_out;

    // ws layout: [meta 256B][perm 64KB][Ag (B+128)*2048 bf16][Wt 4*2048*2048 bf16]
    // hist (1 KB) + cursor (16 B) live in the head of the Ag region: they are
    // dead before gather_convert overwrites Ag. NEED is identical to R1.
    const size_t META_OFF = 0;
    const size_t PERM_OFF = 256;
    const size_t AG_OFF   = PERM_OFF + (size_t)B_TOK * 4;
    const size_t AG_BYTES = (size_t)(B_TOK + 128) * D_IN * 2;
    const size_t WT_OFF   = AG_OFF + AG_BYTES;
    const size_t WT_BYTES = (size_t)L_EXPERTS * D_IN * D_OUT * 2;
    const size_t NEED     = WT_OFF + WT_BYTES;        // ~101.3 MB

    if (ws_size < NEED) {   // launch-invariant branch: graph-safe
        fallback_kernel<<<B_TOK, 256, 0, stream>>>(x, idx, W, b, out);
        return;
    }

    int*      meta   = (int*)((char*)d_ws + META_OFF);
    int*      perm   = (int*)((char*)d_ws + PERM_OFF);
    int*      cursor = (int*)((char*)d_ws + AG_OFF);          // transient
    int*      hist   = (int*)((char*)d_ws + AG_OFF + 256);    // transient
    uint32_t* Ag     = (uint32_t*)((char*)d_ws + AG_OFF);
    ushort*   Wt     = (ushort*)((char*)d_ws + WT_OFF);

    hist_kernel   <<<64, 256, 0, stream>>>(idx, hist);
    prefix_kernel <<<1, 64, 0, stream>>>(hist, meta, cursor);
    scatter_kernel<<<64, 256, 0, stream>>>(idx, cursor, perm);
    gather_convert<<<B_TOK, 256, 0, stream>>>(x, perm, Ag);
    wtrans        <<<dim3(32, 32, L_EXPERTS), 256, 0, stream>>>(W, Wt);
    // m-tile capacity: sum_e ceil(cnt_e/128) <= 131; 17 supertiles x 128 blocks
    gemm_grouped  <<<17 * 128, 256, 0, stream>>>(
        (const ushort*)Ag, Wt, b, meta, perm, out);
}